// Round 7
// baseline (405.629 us; speedup 1.0000x reference)
//
#include <hip/hip_runtime.h>
#include <stdint.h>

#define STENCIL 24
#define EPS_F 1e-4f
#define BLK 256
#define NXCD 8

#define NODE_N 262144                       // nodes per batch (fixed problem size), = 2^18
#define BIN_NODES 2048                      // nodes per bin (LDS accumulator)
#define LBINS 128                           // bins per batch
#define NBINS 256                           // 2 batches * 128
#define BIN_CAP_G 49152                     // per-bin pair capacity: mean 47722, +6.5 sigma

#define S_THREADS 512
#define S_EPT 8
#define EDGES_PER_BLOCK (S_THREADS * S_EPT) // 4096; rec=32KB -> 4 blocks/CU

typedef int   i32x2 __attribute__((ext_vector_type(2)));
typedef float f32x4 __attribute__((ext_vector_type(4)));

// nontemporal load: ONLY for true single-use streams (G, Ao, pairs).
// R8 lesson: do NOT nt-load nbr -- it is read by 3 kernels; plain loads let
// the first reader install it in L3 (48MB << 256MB) so later readers hit L3.
// NOTE: only works on scalar / ext_vector types, NOT HIP_vector_type (float4).
template <typename T>
static __device__ __forceinline__ T ntload(const T* p) {
    return __builtin_nontemporal_load(p);
}

// ---- XCD id (fallback path only), verified gfx950 (learn_hip m09)
static __device__ __forceinline__ int get_xcc_id() {
    int x;
    asm volatile("s_getreg_b32 %0, hwreg(HW_REG_XCC_ID)" : "=s"(x));
    return x & (NXCD - 1);
}

__device__ __forceinline__ float wave_reduce_f32(float v) {
    #pragma unroll
    for (int off = 32; off > 0; off >>= 1)
        v += __shfl_down(v, off, 64);
    return v;
}

// 5-component block(256) reduce, single barrier; out[] valid on thread 0
__device__ __forceinline__ void block_reduce5(float v[5], float out[5]) {
    __shared__ float sw[4][5];
    #pragma unroll
    for (int c = 0; c < 5; ++c) v[c] = wave_reduce_f32(v[c]);
    if ((threadIdx.x & 63) == 0) {
        #pragma unroll
        for (int c = 0; c < 5; ++c) sw[threadIdx.x >> 6][c] = v[c];
    }
    __syncthreads();
    if (threadIdx.x == 0) {
        #pragma unroll
        for (int c = 0; c < 5; ++c)
            out[c] = sw[0][c] + sw[1][c] + sw[2][c] + sw[3][c];
    }
}

// K3: block counting-sort of edges by target bin; dense pair write-out.
// R4 structure (87us): non-returning pass-A histogram ds_add (fire-and-forget)
// + pass-B pos rtn-atomic hidden under G loads. R5's rtn-histogram regressed.
// R8 (kept): pass B single row per thread (t0%8==0 & 24==3*8), contiguous
// unconditional 8-float G run. R9 (kept): nbr PLAIN int4 loads (L3 reuse).
// Diagonal u[i] = wm_i*G_ii piggybacked on j0==0 threads.
__global__ __launch_bounds__(S_THREADS)
void k_sortscatter(const float* __restrict__ G, const float* __restrict__ w,
                   const float* __restrict__ mask, const int* __restrict__ nbr,
                   float* __restrict__ u, int* __restrict__ binCnt,
                   int2* __restrict__ pairs) {
    __shared__ int2 rec[EDGES_PER_BLOCK];    // 32 KB sorted record staging
    __shared__ int hist[LBINS], incl[LBINS], excl[LBINS], pos[LBINS], gb[LBINS];
    int tid = threadIdx.x;
    if (tid < LBINS) hist[tid] = 0;
    __syncthreads();

    long long blockStart = (long long)blockIdx.x * EDGES_PER_BLOCK;
    long long t0 = blockStart + (long long)tid * S_EPT;

    // ---- pass A: neighbors into registers (int4 x2), LDS histogram
    int nb[S_EPT];
    const int4* p4 = (const int4*)(nbr + t0);            // t0 % 16 == 0 -> aligned
    #pragma unroll
    for (int q = 0; q < S_EPT / 4; ++q) {
        int4 x = p4[q];
        nb[q*4] = x.x; nb[q*4+1] = x.y; nb[q*4+2] = x.z; nb[q*4+3] = x.w;
    }
    #pragma unroll
    for (int e = 0; e < S_EPT; ++e) {
        unsigned n = (unsigned)nb[e];
        if (n < (unsigned)NODE_N) atomicAdd(&hist[n >> 11], 1);
    }
    __syncthreads();

    // ---- inclusive scan over 128 bins (Hillis-Steele)
    if (tid < LBINS) incl[tid] = hist[tid];
    __syncthreads();
    for (int d = 1; d < LBINS; d <<= 1) {
        int x = 0;
        if (tid < LBINS && tid >= d) x = incl[tid - d];
        __syncthreads();
        if (tid < LBINS) incl[tid] += x;
        __syncthreads();
    }
    int batchBase = (blockStart >= (long long)NODE_N * STENCIL) ? LBINS : 0;
    if (tid < LBINS) {
        int h = hist[tid];
        int ex = incl[tid] - h;
        excl[tid] = ex;
        pos[tid]  = ex;
        gb[tid]   = h ? atomicAdd(&binCnt[batchBase + tid], h) : 0;
    }
    __syncthreads();

    // ---- pass B: single row per thread; values + diag; LDS scatter at sorted pos
    long long i = t0 / STENCIL;
    int j0 = (int)(t0 - i * STENCIL);                    // in {0, 8, 16}
    float wm = w[i] * mask[i];
    if (j0 == 0) u[i] = wm * G[i * 25];                  // diagonal term
    float gv[S_EPT];
    const float* grow = G + i * 25 + 1 + j0;
    #pragma unroll
    for (int e = 0; e < S_EPT; ++e) gv[e] = grow[e];     // contiguous, unconditional
    #pragma unroll
    for (int e = 0; e < S_EPT; ++e) {
        unsigned n = (unsigned)nb[e];
        if (n < (unsigned)NODE_N) {
            int b = (int)(n >> 11);
            int lp = atomicAdd(&pos[b], 1);
            rec[lp] = make_int2((int)(n & (BIN_NODES - 1)) | (b << 11),
                                __float_as_int(wm * gv[e]));
        }
    }
    __syncthreads();

    // ---- write-out: linear LDS read -> dense per-bin global runs
    int tot = incl[LBINS - 1];
    for (int s = tid; s < tot; s += S_THREADS) {
        int2 r = rec[s];
        int b = (r.x >> 11) & (LBINS - 1);
        int dst = gb[b] + (s - excl[b]);
        if (dst < BIN_CAP_G)
            pairs[(long long)(batchBase + b) * BIN_CAP_G + dst] =
                make_int2(r.x & (BIN_NODES - 1), r.y);
    }
}

// K4: one block per bin; 4-way replicated LDS accumulators (LDS-throughput
// bound: ~48K atomics/CU; replication removes same-address serialization).
__global__ __launch_bounds__(1024)
void k_binaccum(const int* __restrict__ binCnt, const int2* __restrict__ pairs,
                float* __restrict__ u) {
    __shared__ float acc[4][BIN_NODES + 1];  // 32.8 KB
    int g = blockIdx.x, tid = threadIdx.x;
    for (int l = tid; l < BIN_NODES; l += 1024) {
        acc[0][l] = 0.f; acc[1][l] = 0.f; acc[2][l] = 0.f; acc[3][l] = 0.f;
    }
    __syncthreads();
    int cnt = binCnt[g]; if (cnt > BIN_CAP_G) cnt = BIN_CAP_G;
    const i32x2* pb = (const i32x2*)(pairs + (long long)g * BIN_CAP_G);
    int rep = tid & 3;
    for (int s = tid; s < cnt; s += 1024) {
        i32x2 r = __builtin_nontemporal_load(pb + s);
        atomicAdd(&acc[rep][r.x], __int_as_float(r.y));
    }
    __syncthreads();
    long long gbase = (long long)(g >> 7) * NODE_N + (long long)(g & (LBINS - 1)) * BIN_NODES;
    for (int l = tid; l < BIN_NODES; l += 1024)
        u[gbase + l] += acc[0][l] + acc[1][l] + acc[2][l] + acc[3][l];
}

// K5: v_i = u_i*G_ii + sum_j G_ij*u[nbr] + EPS*wm_i.
// G rows staged via LDS (stride-25: gcd(25,32)=1, conflict-free readback).
// R10: UNCHANGED -- control kernel for the k_y de-staging experiment.
__global__ __launch_bounds__(BLK)
void k_v(const float* __restrict__ G, const float* __restrict__ w,
         const float* __restrict__ mask, const int* __restrict__ nbr,
         const float* __restrict__ u, float* __restrict__ v, long long BN) {
    __shared__ float sg[BLK * 25];
    int tid = threadIdx.x;
    long long base = (long long)blockIdx.x * BLK;
    int rows = (int)(((BN - base) < BLK) ? (BN - base) : BLK);
    const float* gsrc = G + base * 25;
    for (int k = tid; k < rows * 25; k += BLK) sg[k] = ntload(gsrc + k);
    __syncthreads();
    if (tid >= rows) return;
    long long i = base + tid;
    const int4* nb4 = (const int4*)(nbr + i * STENCIL);  // 96B rows, 16B aligned
    int nn[24];
    #pragma unroll
    for (int q = 0; q < 6; ++q) {
        int4 x = nb4[q];
        nn[q*4] = x.x; nn[q*4+1] = x.y; nn[q*4+2] = x.z; nn[q*4+3] = x.w;
    }
    const float* g  = sg + tid * 25;
    const float* ub = u + (i / NODE_N) * (long long)NODE_N;
    float uv[STENCIL];
    #pragma unroll
    for (int j = 0; j < STENCIL; ++j)
        uv[j] = ub[(unsigned)nn[j] & (unsigned)(NODE_N - 1)];
    float acc = u[i] * g[0] + EPS_F * ntload(w + i) * ntload(mask + i);
    #pragma unroll
    for (int j = 0; j < STENCIL; ++j)
        acc += g[1 + j] * (((unsigned)nn[j] < (unsigned)NODE_N) ? uv[j] : 0.f);
    v[i] = acc;
}

// K6 (fused): y = A*v; loss partials via algebraic split (no norm needed here):
//   d = (y/nrm - w*m)*m  =>  d^2 = P^2/nrm^2 - 2PQ/nrm + Q^2, P=y*m, Q=w*m^2.
// R10: LDS staging of Ao REMOVED. Rationale: kernel is latency-bound (81us,
// 9.5% HBM, VALUBusy 7%, occ 40%); the staging barrier serialized Ao loads
// against v-gathers and 25.6KB LDS capped blocks/CU. Each thread's Ao row is
// 96B contiguous 16B-aligned -> direct 6x f32x4 (ext-vector for nt builtin).
// Now all ~37 VMEM ops per thread (6 nbr + 24 gathers + 6 Ao + scalars) are
// simultaneously in flight; LDS drops to the 80B reduce scratch.
// Per-block partials: py[0*NB+b]=sum|A|, [1]=sum(m), [2]=sum P^2, [3]=sum PQ, [4]=sum Q^2.
__global__ __launch_bounds__(BLK)
void k_y(const float* __restrict__ Ad, const float* __restrict__ Ao,
         const float* __restrict__ w, const float* __restrict__ mask,
         const int* __restrict__ nbr, const float* __restrict__ v,
         float* __restrict__ py, int nblk, long long BN) {
    int tid = threadIdx.x;
    long long base = (long long)blockIdx.x * BLK;
    int rows = (int)(((BN - base) < BLK) ? (BN - base) : BLK);
    float part[5] = {0.f, 0.f, 0.f, 0.f, 0.f};
    if (tid < rows) {
        long long i = base + tid;
        // 1) neighbor indices (plain loads: nbr is L3-resident, 3rd reader)
        const int4* nb4 = (const int4*)(nbr + i * STENCIL);
        int nn[24];
        #pragma unroll
        for (int q = 0; q < 6; ++q) {
            int4 x = nb4[q];
            nn[q*4] = x.x; nn[q*4+1] = x.y; nn[q*4+2] = x.z; nn[q*4+3] = x.w;
        }
        // 2) issue all 24 v-gathers (branch-free masked index, clustered)
        const float* vb = v + (i / NODE_N) * (long long)NODE_N;
        float vv[STENCIL];
        #pragma unroll
        for (int j = 0; j < STENCIL; ++j)
            vv[j] = vb[(unsigned)nn[j] & (unsigned)(NODE_N - 1)];
        // 3) own A row direct (96B contiguous, 16B aligned) while gathers fly
        float a[STENCIL];
        const f32x4* ar = (const f32x4*)(Ao + i * STENCIL);
        #pragma unroll
        for (int q = 0; q < 6; ++q) {
            f32x4 x = ntload(ar + q);
            a[q*4] = x.x; a[q*4+1] = x.y; a[q*4+2] = x.z; a[q*4+3] = x.w;
        }
        float ad = ntload(Ad + i);
        float m  = ntload(mask + i);
        float wv = ntload(w + i);
        float asum = fabsf(ad);
        #pragma unroll
        for (int j = 0; j < STENCIL; ++j) asum += fabsf(a[j]);
        float acc = v[i] * ad;
        #pragma unroll
        for (int j = 0; j < STENCIL; ++j)
            acc += a[j] * (((unsigned)nn[j] < (unsigned)NODE_N) ? vv[j] : 0.f);
        float P = acc * m;                    // y*m
        float Q = wv * m * m;                 // w*m^2
        part[0] = asum;
        part[1] = m;
        part[2] = P * P;
        part[3] = P * Q;
        part[4] = Q * Q;
    }
    float out[5];
    block_reduce5(part, out);
    if (tid == 0) {
        #pragma unroll
        for (int c = 0; c < 5; ++c) py[(long long)c * nblk + blockIdx.x] = out[c];
    }
}

// K7: final reduce of 5 partial arrays + norm algebra.
__global__ __launch_bounds__(1024)
void k_final(const float* __restrict__ py, int nblk, float* __restrict__ out) {
    __shared__ float sw[16][5];
    __shared__ float res[5];
    float part[5] = {0.f, 0.f, 0.f, 0.f, 0.f};
    for (int t = threadIdx.x; t < nblk; t += 1024) {
        #pragma unroll
        for (int c = 0; c < 5; ++c) part[c] += py[(long long)c * nblk + t];
    }
    #pragma unroll
    for (int c = 0; c < 5; ++c) part[c] = wave_reduce_f32(part[c]);
    if ((threadIdx.x & 63) == 0) {
        #pragma unroll
        for (int c = 0; c < 5; ++c) sw[threadIdx.x >> 6][c] = part[c];
    }
    __syncthreads();
    if (threadIdx.x == 0) {
        #pragma unroll
        for (int c = 0; c < 5; ++c) {
            float r = 0.f;
            for (int k = 0; k < 16; ++k) r += sw[k][c];
            res[c] = r;
        }
        double A   = res[0], act = res[1];
        double a   = res[2], b   = res[3], c2 = res[4];
        double nrm = A / (act * 25.0 + 1e-6) + 1e-8;
        double loss = (a / (nrm * nrm) - 2.0 * b / nrm + c2) / (act + 1e-6);
        out[0] = (float)loss;
    }
}

// ---------------- fallback path (generic shapes): per-XCD privatized scatter --
__global__ void k_init_fb(const float* __restrict__ G, const float* __restrict__ w,
                          const float* __restrict__ mask, float* __restrict__ u, long long BN) {
    long long i = (long long)blockIdx.x * blockDim.x + threadIdx.x;
    if (i < BN) u[i] = w[i] * mask[i] * G[i * 25];
}
__global__ void k_scatter_fb(const float* __restrict__ G, const float* __restrict__ w,
                             const float* __restrict__ mask, const int* __restrict__ nbr,
                             float* __restrict__ ucopy, int N, long long BN) {
    long long t = (long long)blockIdx.x * blockDim.x + threadIdx.x;
    if (t >= BN * STENCIL) return;
    long long i = t / STENCIL;
    int j = (int)(t - i * STENCIL);
    int n = nbr[t];
    if ((unsigned)n >= (unsigned)N) return;
    float wm = w[i] * mask[i];
    float gv = G[i * 25 + 1 + j];
    float* ub = ucopy + (long long)get_xcc_id() * BN + (i / N) * (long long)N;
    __hip_atomic_fetch_add(&ub[n], wm * gv, __ATOMIC_RELAXED, __HIP_MEMORY_SCOPE_WORKGROUP);
}
__global__ void k_usum_fb(const float* __restrict__ ucopy, float* __restrict__ u, long long BN) {
    long long i = (long long)blockIdx.x * blockDim.x + threadIdx.x;
    if (i >= BN) return;
    float acc = u[i];
    #pragma unroll
    for (int c = 0; c < NXCD; ++c) acc += ucopy[(long long)c * BN + i];
    u[i] = acc;
}
// -----------------------------------------------------------------------------

extern "C" void kernel_launch(void* const* d_in, const int* in_sizes, int n_in,
                              void* d_out, int out_size, void* d_ws, size_t ws_size,
                              hipStream_t stream) {
    const float* G    = (const float*)d_in[0];
    const float* Ad   = (const float*)d_in[1];
    const float* Ao   = (const float*)d_in[2];
    const float* w    = (const float*)d_in[3];
    const float* mask = (const float*)d_in[4];
    const int*   nbr  = (const int*)d_in[5];

    const long long BN = in_sizes[3];
    const long long nEdges = BN * STENCIL;
    const int nodeBlocks = (int)((BN + BLK - 1) / BLK);

    // common ws: u, v, py(5*nodeBlocks)
    float* u  = (float*)d_ws;
    float* v  = u + BN;
    float* py = v + BN;
    char*  after_common = (char*)(py + 5LL * nodeBlocks);

    // fast-path extra: binCnt(256) + pairs
    int*  binCnt = (int*)(((uintptr_t)after_common + 15) & ~(uintptr_t)15);
    int2* pairs  = (int2*)(((uintptr_t)(binCnt + NBINS) + 7) & ~(uintptr_t)7);
    size_t need_fast = (size_t)((char*)(pairs + (long long)NBINS * BIN_CAP_G) - (char*)d_ws);

    // fallback extra: ucopy
    float* ucopy = (float*)(((uintptr_t)after_common + 15) & ~(uintptr_t)15);

    bool fast = (BN == 2LL * NODE_N) && (nEdges % EDGES_PER_BLOCK == 0) &&
                (ws_size >= need_fast);

    if (fast) {
        hipMemsetAsync(binCnt, 0, NBINS * sizeof(int), stream);
        int gridS = (int)(nEdges / EDGES_PER_BLOCK);     // 3072
        k_sortscatter<<<gridS, S_THREADS, 0, stream>>>(G, w, mask, nbr, u, binCnt, pairs);
        k_binaccum<<<NBINS, 1024, 0, stream>>>(binCnt, pairs, u);
    } else {
        hipMemsetAsync(ucopy, 0, (size_t)NXCD * BN * sizeof(float), stream);
        int edgeBlocks = (int)((nEdges + BLK - 1) / BLK);
        k_init_fb<<<nodeBlocks, BLK, 0, stream>>>(G, w, mask, u, BN);
        k_scatter_fb<<<edgeBlocks, BLK, 0, stream>>>(G, w, mask, nbr, ucopy, NODE_N, BN);
        k_usum_fb<<<nodeBlocks, BLK, 0, stream>>>(ucopy, u, BN);
    }
    k_v<<<nodeBlocks, BLK, 0, stream>>>(G, w, mask, nbr, u, v, BN);
    k_y<<<nodeBlocks, BLK, 0, stream>>>(Ad, Ao, w, mask, nbr, v, py, nodeBlocks, BN);
    k_final<<<1, 1024, 0, stream>>>(py, nodeBlocks, (float*)d_out);
}

// Round 8
// 400.432 us; speedup vs baseline: 1.0130x; 1.0130x over previous
//
#include <hip/hip_runtime.h>
#include <stdint.h>

#define STENCIL 24
#define EPS_F 1e-4f
#define BLK 256
#define NXCD 8

#define NODE_N 262144                       // nodes per batch (fixed problem size), = 2^18
#define BIN_NODES 2048                      // nodes per bin (LDS accumulator)
#define LBINS 128                           // bins per batch
#define NBINS 256                           // 2 batches * 128
#define BIN_CAP_G 49152                     // per-bin pair capacity: mean 47722, +6.5 sigma

#define S_THREADS 512
#define S_EPT 8
#define EDGES_PER_BLOCK (S_THREADS * S_EPT) // 4096; rec=32KB -> 4 blocks/CU

typedef int   i32x2 __attribute__((ext_vector_type(2)));
typedef float f32x4 __attribute__((ext_vector_type(4)));

// nontemporal load: ONLY for true single-use streams (G, Ao, pairs).
// R8 lesson: do NOT nt-load nbr -- it is read by 3 kernels; plain loads let
// the first reader install it in L3 (48MB << 256MB) so later readers hit L3.
// NOTE: only works on scalar / ext_vector types, NOT HIP_vector_type (float4).
template <typename T>
static __device__ __forceinline__ T ntload(const T* p) {
    return __builtin_nontemporal_load(p);
}

// ---- XCD id (fallback path only), verified gfx950 (learn_hip m09)
static __device__ __forceinline__ int get_xcc_id() {
    int x;
    asm volatile("s_getreg_b32 %0, hwreg(HW_REG_XCC_ID)" : "=s"(x));
    return x & (NXCD - 1);
}

__device__ __forceinline__ float wave_reduce_f32(float v) {
    #pragma unroll
    for (int off = 32; off > 0; off >>= 1)
        v += __shfl_down(v, off, 64);
    return v;
}

// 5-component block(256) reduce, single barrier; out[] valid on thread 0
__device__ __forceinline__ void block_reduce5(float v[5], float out[5]) {
    __shared__ float sw[4][5];
    #pragma unroll
    for (int c = 0; c < 5; ++c) v[c] = wave_reduce_f32(v[c]);
    if ((threadIdx.x & 63) == 0) {
        #pragma unroll
        for (int c = 0; c < 5; ++c) sw[threadIdx.x >> 6][c] = v[c];
    }
    __syncthreads();
    if (threadIdx.x == 0) {
        #pragma unroll
        for (int c = 0; c < 5; ++c)
            out[c] = sw[0][c] + sw[1][c] + sw[2][c] + sw[3][c];
    }
}

// K3: block counting-sort of edges by target bin; dense pair write-out.
// R4 structure (87us): non-returning pass-A histogram ds_add (fire-and-forget)
// + pass-B pos rtn-atomic hidden under G loads. R5's rtn-histogram regressed.
// R8 (kept): pass B single row per thread (t0%8==0 & 24==3*8), contiguous
// unconditional 8-float G run. R9 (kept): nbr PLAIN int4 loads (L3 reuse).
// Diagonal u[i] = wm_i*G_ii piggybacked on j0==0 threads.
__global__ __launch_bounds__(S_THREADS)
void k_sortscatter(const float* __restrict__ G, const float* __restrict__ w,
                   const float* __restrict__ mask, const int* __restrict__ nbr,
                   float* __restrict__ u, int* __restrict__ binCnt,
                   int2* __restrict__ pairs) {
    __shared__ int2 rec[EDGES_PER_BLOCK];    // 32 KB sorted record staging
    __shared__ int hist[LBINS], incl[LBINS], excl[LBINS], pos[LBINS], gb[LBINS];
    int tid = threadIdx.x;
    if (tid < LBINS) hist[tid] = 0;
    __syncthreads();

    long long blockStart = (long long)blockIdx.x * EDGES_PER_BLOCK;
    long long t0 = blockStart + (long long)tid * S_EPT;

    // ---- pass A: neighbors into registers (int4 x2), LDS histogram
    int nb[S_EPT];
    const int4* p4 = (const int4*)(nbr + t0);            // t0 % 16 == 0 -> aligned
    #pragma unroll
    for (int q = 0; q < S_EPT / 4; ++q) {
        int4 x = p4[q];
        nb[q*4] = x.x; nb[q*4+1] = x.y; nb[q*4+2] = x.z; nb[q*4+3] = x.w;
    }
    #pragma unroll
    for (int e = 0; e < S_EPT; ++e) {
        unsigned n = (unsigned)nb[e];
        if (n < (unsigned)NODE_N) atomicAdd(&hist[n >> 11], 1);
    }
    __syncthreads();

    // ---- inclusive scan over 128 bins (Hillis-Steele)
    if (tid < LBINS) incl[tid] = hist[tid];
    __syncthreads();
    for (int d = 1; d < LBINS; d <<= 1) {
        int x = 0;
        if (tid < LBINS && tid >= d) x = incl[tid - d];
        __syncthreads();
        if (tid < LBINS) incl[tid] += x;
        __syncthreads();
    }
    int batchBase = (blockStart >= (long long)NODE_N * STENCIL) ? LBINS : 0;
    if (tid < LBINS) {
        int h = hist[tid];
        int ex = incl[tid] - h;
        excl[tid] = ex;
        pos[tid]  = ex;
        gb[tid]   = h ? atomicAdd(&binCnt[batchBase + tid], h) : 0;
    }
    __syncthreads();

    // ---- pass B: single row per thread; values + diag; LDS scatter at sorted pos
    long long i = t0 / STENCIL;
    int j0 = (int)(t0 - i * STENCIL);                    // in {0, 8, 16}
    float wm = w[i] * mask[i];
    if (j0 == 0) u[i] = wm * G[i * 25];                  // diagonal term
    float gv[S_EPT];
    const float* grow = G + i * 25 + 1 + j0;
    #pragma unroll
    for (int e = 0; e < S_EPT; ++e) gv[e] = grow[e];     // contiguous, unconditional
    #pragma unroll
    for (int e = 0; e < S_EPT; ++e) {
        unsigned n = (unsigned)nb[e];
        if (n < (unsigned)NODE_N) {
            int b = (int)(n >> 11);
            int lp = atomicAdd(&pos[b], 1);
            rec[lp] = make_int2((int)(n & (BIN_NODES - 1)) | (b << 11),
                                __float_as_int(wm * gv[e]));
        }
    }
    __syncthreads();

    // ---- write-out: linear LDS read -> dense per-bin global runs
    int tot = incl[LBINS - 1];
    for (int s = tid; s < tot; s += S_THREADS) {
        int2 r = rec[s];
        int b = (r.x >> 11) & (LBINS - 1);
        int dst = gb[b] + (s - excl[b]);
        if (dst < BIN_CAP_G)
            pairs[(long long)(batchBase + b) * BIN_CAP_G + dst] =
                make_int2(r.x & (BIN_NODES - 1), r.y);
    }
}

// K4: one block per bin; 4-way replicated LDS accumulators (LDS-throughput
// bound: ~48K atomics/CU; replication removes same-address serialization).
__global__ __launch_bounds__(1024)
void k_binaccum(const int* __restrict__ binCnt, const int2* __restrict__ pairs,
                float* __restrict__ u) {
    __shared__ float acc[4][BIN_NODES + 1];  // 32.8 KB
    int g = blockIdx.x, tid = threadIdx.x;
    for (int l = tid; l < BIN_NODES; l += 1024) {
        acc[0][l] = 0.f; acc[1][l] = 0.f; acc[2][l] = 0.f; acc[3][l] = 0.f;
    }
    __syncthreads();
    int cnt = binCnt[g]; if (cnt > BIN_CAP_G) cnt = BIN_CAP_G;
    const i32x2* pb = (const i32x2*)(pairs + (long long)g * BIN_CAP_G);
    int rep = tid & 3;
    for (int s = tid; s < cnt; s += 1024) {
        i32x2 r = __builtin_nontemporal_load(pb + s);
        atomicAdd(&acc[rep][r.x], __int_as_float(r.y));
    }
    __syncthreads();
    long long gbase = (long long)(g >> 7) * NODE_N + (long long)(g & (LBINS - 1)) * BIN_NODES;
    for (int l = tid; l < BIN_NODES; l += 1024)
        u[gbase + l] += acc[0][l] + acc[1][l] + acc[2][l] + acc[3][l];
}

// K5: v_i = u_i*G_ii + sum_j G_ij*u[nbr] + EPS*wm_i.
// G rows staged via LDS (stride-25: gcd(25,32)=1, conflict-free readback).
// R11: UNCHANGED -- control kernel for the k_y2 MLP experiment.
__global__ __launch_bounds__(BLK)
void k_v(const float* __restrict__ G, const float* __restrict__ w,
         const float* __restrict__ mask, const int* __restrict__ nbr,
         const float* __restrict__ u, float* __restrict__ v, long long BN) {
    __shared__ float sg[BLK * 25];
    int tid = threadIdx.x;
    long long base = (long long)blockIdx.x * BLK;
    int rows = (int)(((BN - base) < BLK) ? (BN - base) : BLK);
    const float* gsrc = G + base * 25;
    for (int k = tid; k < rows * 25; k += BLK) sg[k] = ntload(gsrc + k);
    __syncthreads();
    if (tid >= rows) return;
    long long i = base + tid;
    const int4* nb4 = (const int4*)(nbr + i * STENCIL);  // 96B rows, 16B aligned
    int nn[24];
    #pragma unroll
    for (int q = 0; q < 6; ++q) {
        int4 x = nb4[q];
        nn[q*4] = x.x; nn[q*4+1] = x.y; nn[q*4+2] = x.z; nn[q*4+3] = x.w;
    }
    const float* g  = sg + tid * 25;
    const float* ub = u + (i / NODE_N) * (long long)NODE_N;
    float uv[STENCIL];
    #pragma unroll
    for (int j = 0; j < STENCIL; ++j)
        uv[j] = ub[(unsigned)nn[j] & (unsigned)(NODE_N - 1)];
    float acc = u[i] * g[0] + EPS_F * ntload(w + i) * ntload(mask + i);
    #pragma unroll
    for (int j = 0; j < STENCIL; ++j)
        acc += g[1 + j] * (((unsigned)nn[j] < (unsigned)NODE_N) ? uv[j] : 0.f);
    v[i] = acc;
}

// K6b (fast path): y = A*v + loss partials, TWO rows per thread (i, i+NODE_N).
// R11 theory: k_y is latency-bound with insufficient MLP (VALUBusy 4%, 1.15
// TB/s, occ 49% -- R10 showed occupancy/LDS are NOT the constraint). Doubling
// in-flight loads per wave (12 nbr int4 + 48 gathers + 12 Ao quads) halves
// the number of latency-exposed waits per row. nn[] registers retired early
// by packing gather validity into 2 bitmasks (keeps VGPR ~120 -> 16 waves/CU).
__global__ __launch_bounds__(BLK)
void k_y2(const float* __restrict__ Ad, const float* __restrict__ Ao,
          const float* __restrict__ w, const float* __restrict__ mask,
          const int* __restrict__ nbr, const float* __restrict__ v,
          float* __restrict__ py, int nblk) {
    int tid = threadIdx.x;
    long long i0 = (long long)blockIdx.x * BLK + tid;    // batch 0 row
    long long i1 = i0 + NODE_N;                          // batch 1 row
    // 1) both nbr rows (plain loads: L3-resident, 3rd reader)
    int nn0[24], nn1[24];
    const int4* nb40 = (const int4*)(nbr + i0 * STENCIL);
    const int4* nb41 = (const int4*)(nbr + i1 * STENCIL);
    #pragma unroll
    for (int q = 0; q < 6; ++q) {
        int4 x = nb40[q];
        nn0[q*4] = x.x; nn0[q*4+1] = x.y; nn0[q*4+2] = x.z; nn0[q*4+3] = x.w;
    }
    #pragma unroll
    for (int q = 0; q < 6; ++q) {
        int4 x = nb41[q];
        nn1[q*4] = x.x; nn1[q*4+1] = x.y; nn1[q*4+2] = x.z; nn1[q*4+3] = x.w;
    }
    // 2) all 48 gathers issued as one cluster; validity packed so nn dies here
    const float* vb0 = v;
    const float* vb1 = v + NODE_N;
    float vv0[24], vv1[24];
    unsigned valid0 = 0, valid1 = 0;
    #pragma unroll
    for (int j = 0; j < 24; ++j) {
        vv0[j] = vb0[(unsigned)nn0[j] & (unsigned)(NODE_N - 1)];
        valid0 |= ((unsigned)nn0[j] < (unsigned)NODE_N) ? (1u << j) : 0u;
    }
    #pragma unroll
    for (int j = 0; j < 24; ++j) {
        vv1[j] = vb1[(unsigned)nn1[j] & (unsigned)(NODE_N - 1)];
        valid1 |= ((unsigned)nn1[j] < (unsigned)NODE_N) ? (1u << j) : 0u;
    }
    // 3) both A rows direct (96B contiguous, 16B aligned) while gathers fly
    float a0[24], a1[24];
    const f32x4* ar0 = (const f32x4*)(Ao + i0 * STENCIL);
    const f32x4* ar1 = (const f32x4*)(Ao + i1 * STENCIL);
    #pragma unroll
    for (int q = 0; q < 6; ++q) {
        f32x4 x = ntload(ar0 + q);
        a0[q*4] = x.x; a0[q*4+1] = x.y; a0[q*4+2] = x.z; a0[q*4+3] = x.w;
    }
    #pragma unroll
    for (int q = 0; q < 6; ++q) {
        f32x4 x = ntload(ar1 + q);
        a1[q*4] = x.x; a1[q*4+1] = x.y; a1[q*4+2] = x.z; a1[q*4+3] = x.w;
    }
    float ad0 = ntload(Ad + i0),  ad1 = ntload(Ad + i1);
    float m0  = ntload(mask + i0), m1 = ntload(mask + i1);
    float w0  = ntload(w + i0),    w1 = ntload(w + i1);
    float vi0 = v[i0], vi1 = v[i1];
    // 4) compute both rows
    float asum = fabsf(ad0) + fabsf(ad1);
    #pragma unroll
    for (int j = 0; j < 24; ++j) asum += fabsf(a0[j]) + fabsf(a1[j]);
    float acc0 = vi0 * ad0, acc1 = vi1 * ad1;
    #pragma unroll
    for (int j = 0; j < 24; ++j) {
        acc0 += a0[j] * (((valid0 >> j) & 1u) ? vv0[j] : 0.f);
        acc1 += a1[j] * (((valid1 >> j) & 1u) ? vv1[j] : 0.f);
    }
    float P0 = acc0 * m0, P1 = acc1 * m1;
    float Q0 = w0 * m0 * m0, Q1 = w1 * m1 * m1;
    float part[5] = {asum, m0 + m1, P0*P0 + P1*P1, P0*Q0 + P1*Q1, Q0*Q0 + Q1*Q1};
    float out[5];
    block_reduce5(part, out);
    if (tid == 0) {
        #pragma unroll
        for (int c = 0; c < 5; ++c) py[(long long)c * nblk + blockIdx.x] = out[c];
    }
}

// K6 (fallback, generic BN): single-row form (R10).
__global__ __launch_bounds__(BLK)
void k_y(const float* __restrict__ Ad, const float* __restrict__ Ao,
         const float* __restrict__ w, const float* __restrict__ mask,
         const int* __restrict__ nbr, const float* __restrict__ v,
         float* __restrict__ py, int nblk, long long BN) {
    int tid = threadIdx.x;
    long long base = (long long)blockIdx.x * BLK;
    int rows = (int)(((BN - base) < BLK) ? (BN - base) : BLK);
    float part[5] = {0.f, 0.f, 0.f, 0.f, 0.f};
    if (tid < rows) {
        long long i = base + tid;
        const int4* nb4 = (const int4*)(nbr + i * STENCIL);
        int nn[24];
        #pragma unroll
        for (int q = 0; q < 6; ++q) {
            int4 x = nb4[q];
            nn[q*4] = x.x; nn[q*4+1] = x.y; nn[q*4+2] = x.z; nn[q*4+3] = x.w;
        }
        const float* vb = v + (i / NODE_N) * (long long)NODE_N;
        float vv[STENCIL];
        #pragma unroll
        for (int j = 0; j < STENCIL; ++j)
            vv[j] = vb[(unsigned)nn[j] & (unsigned)(NODE_N - 1)];
        float a[STENCIL];
        const f32x4* ar = (const f32x4*)(Ao + i * STENCIL);
        #pragma unroll
        for (int q = 0; q < 6; ++q) {
            f32x4 x = ntload(ar + q);
            a[q*4] = x.x; a[q*4+1] = x.y; a[q*4+2] = x.z; a[q*4+3] = x.w;
        }
        float ad = ntload(Ad + i);
        float m  = ntload(mask + i);
        float wv = ntload(w + i);
        float asum = fabsf(ad);
        #pragma unroll
        for (int j = 0; j < STENCIL; ++j) asum += fabsf(a[j]);
        float acc = v[i] * ad;
        #pragma unroll
        for (int j = 0; j < STENCIL; ++j)
            acc += a[j] * (((unsigned)nn[j] < (unsigned)NODE_N) ? vv[j] : 0.f);
        float P = acc * m;
        float Q = wv * m * m;
        part[0] = asum;
        part[1] = m;
        part[2] = P * P;
        part[3] = P * Q;
        part[4] = Q * Q;
    }
    float out[5];
    block_reduce5(part, out);
    if (tid == 0) {
        #pragma unroll
        for (int c = 0; c < 5; ++c) py[(long long)c * nblk + blockIdx.x] = out[c];
    }
}

// K7: final reduce of 5 partial arrays + norm algebra.
__global__ __launch_bounds__(1024)
void k_final(const float* __restrict__ py, int nblk, float* __restrict__ out) {
    __shared__ float sw[16][5];
    __shared__ float res[5];
    float part[5] = {0.f, 0.f, 0.f, 0.f, 0.f};
    for (int t = threadIdx.x; t < nblk; t += 1024) {
        #pragma unroll
        for (int c = 0; c < 5; ++c) part[c] += py[(long long)c * nblk + t];
    }
    #pragma unroll
    for (int c = 0; c < 5; ++c) part[c] = wave_reduce_f32(part[c]);
    if ((threadIdx.x & 63) == 0) {
        #pragma unroll
        for (int c = 0; c < 5; ++c) sw[threadIdx.x >> 6][c] = part[c];
    }
    __syncthreads();
    if (threadIdx.x == 0) {
        #pragma unroll
        for (int c = 0; c < 5; ++c) {
            float r = 0.f;
            for (int k = 0; k < 16; ++k) r += sw[k][c];
            res[c] = r;
        }
        double A   = res[0], act = res[1];
        double a   = res[2], b   = res[3], c2 = res[4];
        double nrm = A / (act * 25.0 + 1e-6) + 1e-8;
        double loss = (a / (nrm * nrm) - 2.0 * b / nrm + c2) / (act + 1e-6);
        out[0] = (float)loss;
    }
}

// ---------------- fallback path (generic shapes): per-XCD privatized scatter --
__global__ void k_init_fb(const float* __restrict__ G, const float* __restrict__ w,
                          const float* __restrict__ mask, float* __restrict__ u, long long BN) {
    long long i = (long long)blockIdx.x * blockDim.x + threadIdx.x;
    if (i < BN) u[i] = w[i] * mask[i] * G[i * 25];
}
__global__ void k_scatter_fb(const float* __restrict__ G, const float* __restrict__ w,
                             const float* __restrict__ mask, const int* __restrict__ nbr,
                             float* __restrict__ ucopy, int N, long long BN) {
    long long t = (long long)blockIdx.x * blockDim.x + threadIdx.x;
    if (t >= BN * STENCIL) return;
    long long i = t / STENCIL;
    int j = (int)(t - i * STENCIL);
    int n = nbr[t];
    if ((unsigned)n >= (unsigned)N) return;
    float wm = w[i] * mask[i];
    float gv = G[i * 25 + 1 + j];
    float* ub = ucopy + (long long)get_xcc_id() * BN + (i / N) * (long long)N;
    __hip_atomic_fetch_add(&ub[n], wm * gv, __ATOMIC_RELAXED, __HIP_MEMORY_SCOPE_WORKGROUP);
}
__global__ void k_usum_fb(const float* __restrict__ ucopy, float* __restrict__ u, long long BN) {
    long long i = (long long)blockIdx.x * blockDim.x + threadIdx.x;
    if (i >= BN) return;
    float acc = u[i];
    #pragma unroll
    for (int c = 0; c < NXCD; ++c) acc += ucopy[(long long)c * BN + i];
    u[i] = acc;
}
// -----------------------------------------------------------------------------

extern "C" void kernel_launch(void* const* d_in, const int* in_sizes, int n_in,
                              void* d_out, int out_size, void* d_ws, size_t ws_size,
                              hipStream_t stream) {
    const float* G    = (const float*)d_in[0];
    const float* Ad   = (const float*)d_in[1];
    const float* Ao   = (const float*)d_in[2];
    const float* w    = (const float*)d_in[3];
    const float* mask = (const float*)d_in[4];
    const int*   nbr  = (const int*)d_in[5];

    const long long BN = in_sizes[3];
    const long long nEdges = BN * STENCIL;
    const int nodeBlocks = (int)((BN + BLK - 1) / BLK);

    // common ws: u, v, py(5*nodeBlocks)
    float* u  = (float*)d_ws;
    float* v  = u + BN;
    float* py = v + BN;
    char*  after_common = (char*)(py + 5LL * nodeBlocks);

    // fast-path extra: binCnt(256) + pairs
    int*  binCnt = (int*)(((uintptr_t)after_common + 15) & ~(uintptr_t)15);
    int2* pairs  = (int2*)(((uintptr_t)(binCnt + NBINS) + 7) & ~(uintptr_t)7);
    size_t need_fast = (size_t)((char*)(pairs + (long long)NBINS * BIN_CAP_G) - (char*)d_ws);

    // fallback extra: ucopy
    float* ucopy = (float*)(((uintptr_t)after_common + 15) & ~(uintptr_t)15);

    bool fast = (BN == 2LL * NODE_N) && (nEdges % EDGES_PER_BLOCK == 0) &&
                (ws_size >= need_fast);

    if (fast) {
        hipMemsetAsync(binCnt, 0, NBINS * sizeof(int), stream);
        int gridS = (int)(nEdges / EDGES_PER_BLOCK);     // 3072
        k_sortscatter<<<gridS, S_THREADS, 0, stream>>>(G, w, mask, nbr, u, binCnt, pairs);
        k_binaccum<<<NBINS, 1024, 0, stream>>>(binCnt, pairs, u);
        k_v<<<nodeBlocks, BLK, 0, stream>>>(G, w, mask, nbr, u, v, BN);
        int yBlocks = NODE_N / BLK;                       // 1024, 2 rows/thread
        k_y2<<<yBlocks, BLK, 0, stream>>>(Ad, Ao, w, mask, nbr, v, py, yBlocks);
        k_final<<<1, 1024, 0, stream>>>(py, yBlocks, (float*)d_out);
    } else {
        hipMemsetAsync(ucopy, 0, (size_t)NXCD * BN * sizeof(float), stream);
        int edgeBlocks = (int)((nEdges + BLK - 1) / BLK);
        k_init_fb<<<nodeBlocks, BLK, 0, stream>>>(G, w, mask, u, BN);
        k_scatter_fb<<<edgeBlocks, BLK, 0, stream>>>(G, w, mask, nbr, ucopy, NODE_N, BN);
        k_usum_fb<<<nodeBlocks, BLK, 0, stream>>>(ucopy, u, BN);
        k_v<<<nodeBlocks, BLK, 0, stream>>>(G, w, mask, nbr, u, v, BN);
        k_y<<<nodeBlocks, BLK, 0, stream>>>(Ad, Ao, w, mask, nbr, v, py, nodeBlocks, BN);
        k_final<<<1, 1024, 0, stream>>>(py, nodeBlocks, (float*)d_out);
    }
}